// Round 1
// baseline (794.236 us; speedup 1.0000x reference)
//
#include <hip/hip_runtime.h>
#include <math.h>

#define NN 31744        // total nodes B*NODES
#define NE 507904       // input edges (no self loops)
#define NE_TOT 539648   // NE + NN
#define NODES 124
#define NB 256          // graphs
#define CC 32           // channels
#define HC 128          // H*C
#define FEAT_DIM 316
#define NCLS 40
#define NC 3968         // NODES*CC

__device__ __forceinline__ float redsum32(float v) {
#pragma unroll
    for (int m = 16; m >= 1; m >>= 1) v += __shfl_xor(v, m, 64);
    return v;
}

// ---------------- CSR build ----------------
__global__ void init_deg(int* deg) {
    int i = blockIdx.x * blockDim.x + threadIdx.x;
    if (i < NN) deg[i] = 1;  // self loop
}

__global__ void count_deg(const int* __restrict__ ei, int* deg) {
    int e = blockIdx.x * blockDim.x + threadIdx.x;
    if (e < NE) atomicAdd(&deg[ei[NE + e]], 1);
}

__global__ void scan_k(const int* __restrict__ deg, int* __restrict__ row_start) {
    int t = threadIdx.x;             // 1024 threads, NN = 1024*31
    int base = t * 31;
    int s = 0;
    for (int k = 0; k < 31; ++k) s += deg[base + k];
    __shared__ int part[1024];
    part[t] = s;
    __syncthreads();
    for (int off = 1; off < 1024; off <<= 1) {
        int u = (t >= off) ? part[t - off] : 0;
        __syncthreads();
        part[t] += u;
        __syncthreads();
    }
    int pre = part[t] - s;           // exclusive prefix for this chunk
    for (int k = 0; k < 31; ++k) { row_start[base + k] = pre; pre += deg[base + k]; }
    if (t == 1023) row_start[NN] = part[1023];
}

__global__ void fill_self(const int* __restrict__ row_start, int* cursor, int* colx) {
    int i = blockIdx.x * blockDim.x + threadIdx.x;
    if (i < NN) { cursor[i] = 1; colx[row_start[i]] = i; }
}

__global__ void fill_edges(const int* __restrict__ ei, const int* __restrict__ row_start,
                           int* cursor, int* colx) {
    int e = blockIdx.x * blockDim.x + threadIdx.x;
    if (e < NE) {
        int s = ei[e], d = ei[NE + e];
        int p = atomicAdd(&cursor[d], 1);
        colx[row_start[d] + p] = s;
    }
}

// ---------------- per-layer kernels ----------------
// h[NN][128] = x[NN][32] @ W[32][128]
__global__ void gemm_h(const float* __restrict__ x, const float* __restrict__ W,
                       float* __restrict__ h) {
    int idx = blockIdx.x * blockDim.x + threadIdx.x;
    if (idx >= NN * HC) return;
    int r = idx >> 7, c = idx & 127;
    const float* xr = x + r * CC;
    float s = 0.f;
#pragma unroll
    for (int k = 0; k < CC; ++k) s += xr[k] * W[k * HC + c];
    h[idx] = s;
}

// fused SuperGAT-MX attention + online softmax + aggregation + head mean + bias
// one block (128 thr) per dst node; thread = (head = t>>5, chan = t&31)
__global__ void conv_fused(const float* __restrict__ h, const int* __restrict__ row_start,
                           const int* __restrict__ colx, const float* __restrict__ att_l,
                           const float* __restrict__ att_r, const float* __restrict__ bias,
                           float* __restrict__ y) {
    int node = blockIdx.x;
    int t = threadIdx.x;
    int c = t & 31;
    float xi = h[node * HC + t];
    float wl = att_l[t];             // att_l[h][c], t = h*32+c
    float wr = att_r[t];
    float ar = redsum32(xi * wr);    // dot(x_i, att_r[h]), same in all 32 lanes of group
    int e0 = row_start[node], e1 = row_start[node + 1];
    float m = -INFINITY, s = 0.f, acc = 0.f;
    for (int e = e0; e < e1; ++e) {
        int src = colx[e];
        float xj = h[src * HC + t];
        float logit = redsum32(xi * xj);
        float al = redsum32(xj * wl);
        float sig = 1.f / (1.f + __expf(-logit));
        float alpha = (al + ar) * sig;
        alpha = alpha >= 0.f ? alpha : 0.2f * alpha;     // leaky_relu 0.2
        float nm = fmaxf(m, alpha);
        float f = __expf(m - nm);      // m=-inf first iter -> 0
        float p = __expf(alpha - nm);
        acc = acc * f + p * xj;
        s = s * f + p;
        m = nm;
    }
    float out = acc / (s + 1e-16f);
    __shared__ float tmp[128];
    tmp[t] = out;
    __syncthreads();
    if (t < 32) {
        float v = 0.25f * (tmp[t] + tmp[32 + t] + tmp[64 + t] + tmp[96 + t]) + bias[t];
        y[node * CC + t] = v;
    }
}

// partial BN stats: acc[0..31]=sum, acc[32..63]=sumsq
__global__ void bnstats(const float* __restrict__ y, float* __restrict__ acc) {
    int t = threadIdx.x;
    int c = t & 31;
    float s = 0.f, q = 0.f;
    for (int i = blockIdx.x * blockDim.x + t; i < NN * CC; i += gridDim.x * blockDim.x) {
        float v = y[i]; s += v; q += v * v;
    }
    __shared__ float ls[256], lq[256];
    ls[t] = s; lq[t] = q;
    __syncthreads();
    if (t < 32) {
        float S = 0.f, Q = 0.f;
        for (int k = t; k < 256; k += 32) { S += ls[k]; Q += lq[k]; }
        atomicAdd(&acc[c], S);
        atomicAdd(&acc[32 + c], Q);
    }
}

// BN + relu -> xout; per-graph mean/max pool -> feat[., 124 + l*64 ...]
__global__ void bn_relu_pool(const float* __restrict__ y, const float* __restrict__ acc,
                             const float* __restrict__ gamma, const float* __restrict__ beta,
                             float* __restrict__ xout, float* __restrict__ feat, int l) {
    int g = blockIdx.x;
    int t = threadIdx.x;          // 128
    int c = t & 31, r0 = t >> 5;
    float mu = acc[c] * (1.f / NN);
    float var = acc[32 + c] * (1.f / NN) - mu * mu;
    float sc = rsqrtf(var + 1e-5f) * gamma[c];
    float bt = beta[c];
    float s = 0.f, mx = -INFINITY;
    for (int r = r0; r < NODES; r += 4) {
        int i = (g * NODES + r) * CC + c;
        float v = (y[i] - mu) * sc + bt;
        v = fmaxf(v, 0.f);
        xout[i] = v;
        s += v; mx = fmaxf(mx, v);
    }
    __shared__ float ls[128], lm[128];
    ls[t] = s; lm[t] = mx;
    __syncthreads();
    if (t < 32) {
        float S = ls[t] + ls[32 + t] + ls[64 + t] + ls[96 + t];
        float M = fmaxf(fmaxf(lm[t], lm[32 + t]), fmaxf(lm[64 + t], lm[96 + t]));
        float* fp = feat + g * FEAT_DIM + NODES + l * 64;
        fp[t] = S * (1.f / NODES);
        fp[32 + t] = M;
    }
}

// out1[NB][124] = X(NB,3968) @ W(3968,124) + b  ; 4 graphs per block
#define LBT 4
__global__ void lin1_k(const float* __restrict__ X, const float* __restrict__ W,
                       const float* __restrict__ b, float* __restrict__ out1) {
    int gb = blockIdx.x * LBT;
    int t = threadIdx.x;  // 128
    __shared__ float xs[LBT][128];
    float accv[LBT] = {0.f, 0.f, 0.f, 0.f};
    for (int k0 = 0; k0 < NC; k0 += 128) {
        __syncthreads();
        for (int i = t; i < LBT * 128; i += 128) {
            int rr = i >> 7, kk = i & 127;
            xs[rr][kk] = X[(gb + rr) * NC + k0 + kk];
        }
        __syncthreads();
        if (t < 124) {
            for (int kk = 0; kk < 128; ++kk) {
                float w = W[(k0 + kk) * 124 + t];
#pragma unroll
                for (int rr = 0; rr < LBT; ++rr) accv[rr] += xs[rr][kk] * w;
            }
        }
    }
    if (t < 124) {
#pragma unroll
        for (int rr = 0; rr < LBT; ++rr) out1[(gb + rr) * 124 + t] = accv[rr] + b[t];
    }
}

// bn over B rows of out1 + relu -> feat[., 0..123]
__global__ void bn1_relu(const float* __restrict__ out1, const float* __restrict__ gamma,
                         const float* __restrict__ beta, float* __restrict__ feat) {
    int c = threadIdx.x;
    if (c >= 124) return;
    float s = 0.f, q = 0.f;
    for (int b = 0; b < NB; ++b) { float v = out1[b * 124 + c]; s += v; q += v * v; }
    float mu = s * (1.f / NB);
    float var = q * (1.f / NB) - mu * mu;
    float sc = rsqrtf(var + 1e-5f) * gamma[c];
    float bt = beta[c];
    for (int b = 0; b < NB; ++b) {
        float v = (out1[b * 124 + c] - mu) * sc + bt;
        feat[b * FEAT_DIM + c] = fmaxf(v, 0.f);
    }
}

__global__ void lin2_k(const float* __restrict__ feat, const float* __restrict__ W,
                       const float* __restrict__ b, float* __restrict__ out) {
    int idx = blockIdx.x * blockDim.x + threadIdx.x;
    if (idx >= NB * NCLS) return;
    int g = idx / NCLS, j = idx % NCLS;
    const float* f = feat + g * FEAT_DIM;
    float s = b[j];
    for (int k = 0; k < FEAT_DIM; ++k) s += f[k] * W[k * NCLS + j];
    out[idx] = s;
}

extern "C" void kernel_launch(void* const* d_in, const int* in_sizes, int n_in,
                              void* d_out, int out_size, void* d_ws, size_t ws_size,
                              hipStream_t stream) {
    const float* x       = (const float*)d_in[0];
    const int*   ei      = (const int*)d_in[1];
    const float* conv_W  = (const float*)d_in[3];
    const float* att_l   = (const float*)d_in[4];
    const float* att_r   = (const float*)d_in[5];
    const float* conv_b  = (const float*)d_in[6];
    const float* bn_g    = (const float*)d_in[7];
    const float* bn_b    = (const float*)d_in[8];
    const float* lin1_W  = (const float*)d_in[9];
    const float* lin1_b  = (const float*)d_in[10];
    const float* bn1_g   = (const float*)d_in[11];
    const float* bn1_b   = (const float*)d_in[12];
    const float* lin2_W  = (const float*)d_in[13];
    const float* lin2_b  = (const float*)d_in[14];

    float* ws = (float*)d_ws;
    float* h      = ws;                    // NN*128
    float* y      = h + (size_t)NN * HC;   // NN*32
    float* xbuf   = y + (size_t)NN * CC;   // NN*32
    float* bnacc  = xbuf + (size_t)NN * CC;  // 64
    float* feat   = bnacc + 64;            // NB*316
    float* out1   = feat + NB * FEAT_DIM;  // NB*124
    int* deg       = (int*)(out1 + NB * 124);  // NN
    int* row_start = deg + NN;                 // NN+1
    int* cursor    = row_start + NN + 1;       // NN
    int* colx      = cursor + NN;              // NE_TOT

    // CSR build
    init_deg<<<(NN + 255) / 256, 256, 0, stream>>>(deg);
    count_deg<<<(NE + 255) / 256, 256, 0, stream>>>(ei, deg);
    scan_k<<<1, 1024, 0, stream>>>(deg, row_start);
    fill_self<<<(NN + 255) / 256, 256, 0, stream>>>(row_start, cursor, colx);
    fill_edges<<<(NE + 255) / 256, 256, 0, stream>>>(ei, row_start, cursor, colx);

    const float* xin = x;
    for (int l = 0; l < 3; ++l) {
        gemm_h<<<(NN * HC + 255) / 256, 256, 0, stream>>>(xin, conv_W + l * CC * HC, h);
        conv_fused<<<NN, 128, 0, stream>>>(h, row_start, colx,
                                           att_l + l * HC, att_r + l * HC,
                                           conv_b + l * CC, y);
        hipMemsetAsync(bnacc, 0, 64 * sizeof(float), stream);
        bnstats<<<256, 256, 0, stream>>>(y, bnacc);
        bn_relu_pool<<<NB, 128, 0, stream>>>(y, bnacc, bn_g + l * CC, bn_b + l * CC,
                                             xbuf, feat, l);
        xin = xbuf;
    }

    lin1_k<<<NB / LBT, 128, 0, stream>>>(xbuf, lin1_W, lin1_b, out1);
    bn1_relu<<<1, 128, 0, stream>>>(out1, bn1_g, bn1_b, feat);
    lin2_k<<<(NB * NCLS + 255) / 256, 256, 0, stream>>>(feat, lin2_W, lin2_b, (float*)d_out);
}

// Round 2
// 439.953 us; speedup vs baseline: 1.8053x; 1.8053x over previous
//
#include <hip/hip_runtime.h>
#include <math.h>

#define NN 31744        // total nodes B*NODES
#define NE 507904       // input edges (no self loops)
#define NE_TOT 539648   // NE + NN
#define NODES 124
#define NB 256          // graphs
#define CC 32           // channels
#define HC 128          // H*C
#define HCP 132         // padded h row (bank-conflict)
#define FEAT_DIM 316
#define NCLS 40
#define NC 3968         // NODES*CC

__device__ __forceinline__ float redsum32(float v) {
#pragma unroll
    for (int m = 16; m >= 1; m >>= 1) v += __shfl_xor(v, m, 64);
    return v;
}

// ---------------- CSR build ----------------
__global__ void init_deg(int* deg) {
    int i = blockIdx.x * blockDim.x + threadIdx.x;
    if (i < NN) deg[i] = 1;  // self loop
}

__global__ void count_deg(const int* __restrict__ ei, int* deg) {
    int e = blockIdx.x * blockDim.x + threadIdx.x;
    if (e < NE) atomicAdd(&deg[ei[NE + e]], 1);
}

__global__ void scan_k(const int* __restrict__ deg, int* __restrict__ row_start) {
    int t = threadIdx.x;             // 1024 threads, NN = 1024*31
    int base = t * 31;
    int s = 0;
    for (int k = 0; k < 31; ++k) s += deg[base + k];
    __shared__ int part[1024];
    part[t] = s;
    __syncthreads();
    for (int off = 1; off < 1024; off <<= 1) {
        int u = (t >= off) ? part[t - off] : 0;
        __syncthreads();
        part[t] += u;
        __syncthreads();
    }
    int pre = part[t] - s;           // exclusive prefix for this chunk
    for (int k = 0; k < 31; ++k) { row_start[base + k] = pre; pre += deg[base + k]; }
    if (t == 1023) row_start[NN] = part[1023];
}

__global__ void fill_self(const int* __restrict__ row_start, int* cursor, int* colx) {
    int i = blockIdx.x * blockDim.x + threadIdx.x;
    if (i < NN) { cursor[i] = 1; colx[row_start[i]] = i; }
}

__global__ void fill_edges(const int* __restrict__ ei, const int* __restrict__ row_start,
                           int* cursor, int* colx) {
    int e = blockIdx.x * blockDim.x + threadIdx.x;
    if (e < NE) {
        int s = ei[e], d = ei[NE + e];
        int p = atomicAdd(&cursor[d], 1);
        colx[row_start[d] + p] = s;
    }
}

// ---------------- fused per-graph layer kernel ----------------
// block = 1 graph (1024 threads, 16 waves); LDS-resident h; fused:
//   h = x@W ; AL/AR = h·att ; per-node attention softmax+aggregate ; BN partial stats
__global__ __launch_bounds__(1024, 1) void conv_graph(
    const float* __restrict__ xin, const float* __restrict__ W,
    const float* __restrict__ attl, const float* __restrict__ attr,
    const float* __restrict__ bias,
    const int* __restrict__ row_start, const int* __restrict__ colx,
    float* __restrict__ y, float* __restrict__ bnacc) {
    __shared__ float xs[NODES][CC];      // 15.9 KB
    __shared__ float Ws[CC][HC];         // 16 KB
    __shared__ float hs[NODES][HCP];     // 64 KB (padded: stride 132)
    __shared__ float ALs[NODES][4], ARs[NODES][4];
    __shared__ float alw[HC], arw[HC];
    __shared__ float bsum[16][CC], bsq[16][CC];

    int g = blockIdx.x;
    int t = threadIdx.x;
    int base = g * NODES;

    for (int i = t; i < NODES * CC; i += 1024) xs[i >> 5][i & 31] = xin[base * CC + i];
    for (int i = t; i < CC * HC; i += 1024) Ws[i >> 7][i & 127] = W[i];
    if (t < HC) { alw[t] = attl[t]; arw[t] = attr[t]; }
    __syncthreads();

    // h = x @ W  (in LDS)
    for (int i = t; i < NODES * HC; i += 1024) {
        int n = i >> 7, hc = i & 127;
        float s = 0.f;
#pragma unroll
        for (int k = 0; k < CC; ++k) s += xs[n][k] * Ws[k][hc];
        hs[n][hc] = s;
    }
    __syncthreads();

    // per-node attention scalars AL[n][h], AR[n][h]
    for (int i = t; i < NODES * 4; i += 1024) {
        int n = i >> 2, hh = i & 3;
        float a = 0.f, b = 0.f;
#pragma unroll
        for (int k = 0; k < CC; ++k) {
            float v = hs[n][hh * 32 + k];
            a += v * alw[hh * 32 + k];
            b += v * arw[hh * 32 + k];
        }
        ALs[n][hh] = a; ARs[n][hh] = b;
    }
    __syncthreads();

    // edge loop: one wave per node; lane = (h0 = lane>>5, c = lane&31), slots {h0, h0+2}
    int wave = t >> 6;
    int lane = t & 63;
    int h0 = lane >> 5;
    int c = lane & 31;
    float bs = 0.f, bq = 0.f;
    for (int n = wave; n < NODES; n += 16) {
        float xi0 = hs[n][h0 * 32 + c];
        float xi1 = hs[n][h0 * 32 + 64 + c];
        float ar0 = ARs[n][h0], ar1 = ARs[n][h0 + 2];
        int e0 = row_start[base + n], e1 = row_start[base + n + 1];
        float s0 = 0.f, s1 = 0.f, acc0 = 0.f, acc1 = 0.f;
        for (int e = e0; e < e1; ++e) {
            int src = colx[e] - base;
            float xj0 = hs[src][h0 * 32 + c];
            float xj1 = hs[src][h0 * 32 + 64 + c];
            float l0 = redsum32(xi0 * xj0);
            float l1 = redsum32(xi1 * xj1);
            float a0 = (ALs[src][h0]     + ar0) * __builtin_amdgcn_rcpf(1.f + __expf(-l0));
            float a1 = (ALs[src][h0 + 2] + ar1) * __builtin_amdgcn_rcpf(1.f + __expf(-l1));
            a0 = a0 >= 0.f ? a0 : 0.2f * a0;           // leaky_relu(0.2)
            a1 = a1 >= 0.f ? a1 : 0.2f * a1;
            float p0 = __expf(a0), p1 = __expf(a1);    // |a| small: no max-shift needed
            acc0 += p0 * xj0;  s0 += p0;
            acc1 += p1 * xj1;  s1 += p1;
        }
        float o = acc0 / (s0 + 1e-16f) + acc1 / (s1 + 1e-16f);
        o += __shfl_xor(o, 32, 64);                    // add other head pair
        float v = 0.25f * o + bias[c];
        if (lane < 32) {
            y[(base + n) * CC + c] = v;
            bs += v; bq += v * v;
        }
    }
    // BN partial stats
    if (lane < 32) { bsum[wave][c] = bs; bsq[wave][c] = bq; }
    __syncthreads();
    if (t < CC) {
        float S = 0.f, Q = 0.f;
        for (int w = 0; w < 16; ++w) { S += bsum[w][t]; Q += bsq[w][t]; }
        atomicAdd(&bnacc[t], S);
        atomicAdd(&bnacc[CC + t], Q);
    }
}

// BN + relu -> xout; per-graph mean/max pool -> feat[., 124 + l*64 ...]
__global__ void bn_relu_pool(const float* __restrict__ y, const float* __restrict__ acc,
                             const float* __restrict__ gamma, const float* __restrict__ beta,
                             float* __restrict__ xout, float* __restrict__ feat, int l) {
    int g = blockIdx.x;
    int t = threadIdx.x;          // 128
    int c = t & 31, r0 = t >> 5;
    float mu = acc[c] * (1.f / NN);
    float var = acc[32 + c] * (1.f / NN) - mu * mu;
    float sc = rsqrtf(var + 1e-5f) * gamma[c];
    float bt = beta[c];
    float s = 0.f, mx = -INFINITY;
    for (int r = r0; r < NODES; r += 4) {
        int i = (g * NODES + r) * CC + c;
        float v = (y[i] - mu) * sc + bt;
        v = fmaxf(v, 0.f);
        xout[i] = v;
        s += v; mx = fmaxf(mx, v);
    }
    __shared__ float ls[128], lm[128];
    ls[t] = s; lm[t] = mx;
    __syncthreads();
    if (t < 32) {
        float S = ls[t] + ls[32 + t] + ls[64 + t] + ls[96 + t];
        float M = fmaxf(fmaxf(lm[t], lm[32 + t]), fmaxf(lm[64 + t], lm[96 + t]));
        float* fp = feat + g * FEAT_DIM + NODES + l * 64;
        fp[t] = S * (1.f / NODES);
        fp[32 + t] = M;
    }
}

// ---------------- classifier head ----------------
#define L1_GPB 4
#define L1_KS 4
#define L1_KCH 992   // NC / L1_KS
// grid = (NB/L1_GPB)*L1_KS = 256 blocks, 128 threads
__global__ void lin1_part(const float* __restrict__ X, const float* __restrict__ W,
                          float* __restrict__ part) {
    int ks = blockIdx.x & (L1_KS - 1);
    int gb = (blockIdx.x >> 2) * L1_GPB;
    int t = threadIdx.x;
    int kbeg = ks * L1_KCH;
    __shared__ float xs[L1_GPB][124];
    float acc[L1_GPB] = {0.f, 0.f, 0.f, 0.f};
    for (int k0 = kbeg; k0 < kbeg + L1_KCH; k0 += 124) {
        __syncthreads();
        if (t < 124) {
#pragma unroll
            for (int rr = 0; rr < L1_GPB; ++rr) xs[rr][t] = X[(gb + rr) * NC + k0 + t];
        }
        __syncthreads();
        if (t < 124) {
            for (int kk = 0; kk < 124; ++kk) {
                float w = W[(k0 + kk) * 124 + t];
#pragma unroll
                for (int rr = 0; rr < L1_GPB; ++rr) acc[rr] += xs[rr][kk] * w;
            }
        }
    }
    if (t < 124)
#pragma unroll
        for (int rr = 0; rr < L1_GPB; ++rr)
            part[(ks * NB + gb + rr) * 124 + t] = acc[rr];
}

__global__ void lin1_reduce(const float* __restrict__ part, const float* __restrict__ b,
                            float* __restrict__ out1) {
    int i = blockIdx.x * blockDim.x + threadIdx.x;
    if (i >= NB * 124) return;
    int j = i % 124;
    float s = b[j];
#pragma unroll
    for (int ks = 0; ks < L1_KS; ++ks) s += part[ks * NB * 124 + i];
    out1[i] = s;
}

__global__ void bn1_relu(const float* __restrict__ out1, const float* __restrict__ gamma,
                         const float* __restrict__ beta, float* __restrict__ feat) {
    int c = threadIdx.x;
    if (c >= 124) return;
    float s = 0.f, q = 0.f;
    for (int b = 0; b < NB; ++b) { float v = out1[b * 124 + c]; s += v; q += v * v; }
    float mu = s * (1.f / NB);
    float var = q * (1.f / NB) - mu * mu;
    float sc = rsqrtf(var + 1e-5f) * gamma[c];
    float bt = beta[c];
    for (int b = 0; b < NB; ++b) {
        float v = (out1[b * 124 + c] - mu) * sc + bt;
        feat[b * FEAT_DIM + c] = fmaxf(v, 0.f);
    }
}

__global__ void lin2_k(const float* __restrict__ feat, const float* __restrict__ W,
                       const float* __restrict__ b, float* __restrict__ out) {
    int idx = blockIdx.x * blockDim.x + threadIdx.x;
    if (idx >= NB * NCLS) return;
    int g = idx / NCLS, j = idx % NCLS;
    const float* f = feat + g * FEAT_DIM;
    float s = b[j];
    for (int k = 0; k < FEAT_DIM; ++k) s += f[k] * W[k * NCLS + j];
    out[idx] = s;
}

extern "C" void kernel_launch(void* const* d_in, const int* in_sizes, int n_in,
                              void* d_out, int out_size, void* d_ws, size_t ws_size,
                              hipStream_t stream) {
    const float* x      = (const float*)d_in[0];
    const int*   ei     = (const int*)d_in[1];
    const float* conv_W = (const float*)d_in[3];
    const float* att_l  = (const float*)d_in[4];
    const float* att_r  = (const float*)d_in[5];
    const float* conv_b = (const float*)d_in[6];
    const float* bn_g   = (const float*)d_in[7];
    const float* bn_b   = (const float*)d_in[8];
    const float* lin1_W = (const float*)d_in[9];
    const float* lin1_b = (const float*)d_in[10];
    const float* bn1_g  = (const float*)d_in[11];
    const float* bn1_b  = (const float*)d_in[12];
    const float* lin2_W = (const float*)d_in[13];
    const float* lin2_b = (const float*)d_in[14];

    float* ws = (float*)d_ws;
    float* y     = ws;                         // NN*32
    float* xbuf  = y + (size_t)NN * CC;        // NN*32
    float* bnacc = xbuf + (size_t)NN * CC;     // 64
    float* feat  = bnacc + 64;                 // NB*316
    float* out1  = feat + NB * FEAT_DIM;       // NB*124
    float* part  = out1 + NB * 124;            // 4*NB*124
    int* deg       = (int*)(part + L1_KS * NB * 124);
    int* row_start = deg + NN;
    int* cursor    = row_start + NN + 1;
    int* colx      = cursor + NN;

    // CSR build
    init_deg<<<(NN + 255) / 256, 256, 0, stream>>>(deg);
    count_deg<<<(NE + 255) / 256, 256, 0, stream>>>(ei, deg);
    scan_k<<<1, 1024, 0, stream>>>(deg, row_start);
    fill_self<<<(NN + 255) / 256, 256, 0, stream>>>(row_start, cursor, colx);
    fill_edges<<<(NE + 255) / 256, 256, 0, stream>>>(ei, row_start, cursor, colx);

    const float* xin = x;
    for (int l = 0; l < 3; ++l) {
        hipMemsetAsync(bnacc, 0, 64 * sizeof(float), stream);
        conv_graph<<<NB, 1024, 0, stream>>>(xin, conv_W + l * CC * HC,
                                            att_l + l * HC, att_r + l * HC,
                                            conv_b + l * CC, row_start, colx, y, bnacc);
        bn_relu_pool<<<NB, 128, 0, stream>>>(y, bnacc, bn_g + l * CC, bn_b + l * CC,
                                             xbuf, feat, l);
        xin = xbuf;
    }

    lin1_part<<<(NB / L1_GPB) * L1_KS, 128, 0, stream>>>(xbuf, lin1_W, part);
    lin1_reduce<<<(NB * 124 + 255) / 256, 256, 0, stream>>>(part, lin1_b, out1);
    bn1_relu<<<1, 128, 0, stream>>>(out1, bn1_g, bn1_b, feat);
    lin2_k<<<(NB * NCLS + 255) / 256, 256, 0, stream>>>(feat, lin2_W, lin2_b, (float*)d_out);
}

// Round 3
// 403.658 us; speedup vs baseline: 1.9676x; 1.0899x over previous
//
#include <hip/hip_runtime.h>
#include <math.h>

#define NN 31744        // total nodes B*NODES
#define NE 507904       // input edges (no self loops)
#define NE_TOT 539648   // NE + NN
#define NODES 124
#define NB 256          // graphs
#define CC 32           // channels
#define HC 128          // H*C
#define FEAT_DIM 316
#define NCLS 40
#define NC 3968         // NODES*CC

// ---------------- CSR build ----------------
__global__ void init_deg(int* deg) {
    int i = blockIdx.x * blockDim.x + threadIdx.x;
    if (i < NN) deg[i] = 1;  // self loop
}

__global__ void count_deg(const int* __restrict__ ei, int* deg) {
    int e = blockIdx.x * blockDim.x + threadIdx.x;
    if (e < NE) atomicAdd(&deg[ei[NE + e]], 1);
}

__global__ void scan_k(const int* __restrict__ deg, int* __restrict__ row_start) {
    int t = threadIdx.x;             // 1024 threads, NN = 1024*31
    int base = t * 31;
    int s = 0;
    for (int k = 0; k < 31; ++k) s += deg[base + k];
    __shared__ int part[1024];
    part[t] = s;
    __syncthreads();
    for (int off = 1; off < 1024; off <<= 1) {
        int u = (t >= off) ? part[t - off] : 0;
        __syncthreads();
        part[t] += u;
        __syncthreads();
    }
    int pre = part[t] - s;           // exclusive prefix for this chunk
    for (int k = 0; k < 31; ++k) { row_start[base + k] = pre; pre += deg[base + k]; }
    if (t == 1023) row_start[NN] = part[1023];
}

__global__ void fill_self(const int* __restrict__ row_start, int* cursor, int* colx) {
    int i = blockIdx.x * blockDim.x + threadIdx.x;
    if (i < NN) { cursor[i] = 1; colx[row_start[i]] = i; }
}

__global__ void fill_edges(const int* __restrict__ ei, const int* __restrict__ row_start,
                           int* cursor, int* colx) {
    int e = blockIdx.x * blockDim.x + threadIdx.x;
    if (e < NE) {
        int s = ei[e], d = ei[NE + e];
        int p = atomicAdd(&cursor[d], 1);
        colx[row_start[d] + p] = s;
    }
}

// ---------------- fused per-graph layer kernel ----------------
// block = 1 graph (1024 threads, 16 waves). Phases:
//  H = x@W (LDS)  ->  AL/AR  ->  per head: [transpose slice -> dense Gram S ->
//  dense P = exp(leaky((AL_j+AR_i)*sigmoid(S))) -> sparse CSR aggregation, reg accum]
//  -> y write + BN partial stats.  No shuffles, no per-edge transcendentals.
__global__ __launch_bounds__(1024, 1) void conv_graph(
    const float* __restrict__ xin, const float* __restrict__ W,
    const float* __restrict__ attl, const float* __restrict__ attr,
    const float* __restrict__ bias,
    const int* __restrict__ row_start, const int* __restrict__ colx,
    float* __restrict__ y, float* __restrict__ bnacc) {

    __shared__ float hs[NODES][HC];                 // 63.5 KB
    __shared__ float S[128][128];                   // 65.5 KB (xs overlays)
    __shared__ float Ht[32][132];                   // 16.9 KB (Ws overlays)
    __shared__ float ALs[4][128], ARs[4][128];      // 4 KB
    __shared__ float alw[HC], arw[HC];              // 1 KB
    __shared__ float bsum[16][2][CC], bsq[16][2][CC]; // 8 KB
    __shared__ float bias_s[CC];

    int g = blockIdx.x, t = threadIdx.x, base = g * NODES;
    float* xs = &S[0][0];                           // [124][32] overlay

    // ---- stage ----
    {
        const float4* src = (const float4*)(xin + (size_t)base * CC);
        float4* dst = (float4*)xs;
        for (int i = t; i < NODES * CC / 4; i += 1024) dst[i] = src[i];
    }
    for (int i = t; i < CC * HC; i += 1024) Ht[i >> 7][i & 127] = W[i];  // Ws overlay
    if (t < HC) { alw[t] = attl[t]; arw[t] = attr[t]; }
    if (t < CC) bias_s[t] = bias[t];
    __syncthreads();

    // ---- H = x @ W ----
    {
        int hc = t & 127;
        int n0 = t >> 7;   // 0..7
        float wreg[CC];
#pragma unroll
        for (int k = 0; k < CC; ++k) wreg[k] = Ht[k][hc];
        for (int n = n0; n < NODES; n += 8) {
            const float4* xr = (const float4*)&xs[n * CC];
            float s = 0.f;
#pragma unroll
            for (int q = 0; q < 8; ++q) {
                float4 a = xr[q];
                s += a.x * wreg[4*q] + a.y * wreg[4*q+1] + a.z * wreg[4*q+2] + a.w * wreg[4*q+3];
            }
            hs[n][hc] = s;
        }
    }
    __syncthreads();

    // ---- AL/AR per (head, node) ----
    if (t < 512) {
        int n = t >> 2, hh = t & 3;
        float a = 0.f, b = 0.f;
        if (n < NODES) {
#pragma unroll
            for (int k = 0; k < CC; ++k) {
                float v = hs[n][hh * 32 + k];
                a += v * alw[hh * 32 + k];
                b += v * arw[hh * 32 + k];
            }
        }
        ALs[hh][n] = a; ARs[hh][n] = b;
    }

    int wv = t >> 6, lane = t & 63;
    int sslot = lane >> 5, c = lane & 31;
    int ti = wv >> 2, tj = wv & 3;
    int gi = ti * 32 + (lane >> 3) * 4;
    int gj = tj * 32 + (lane & 7) * 4;
    float acc[4] = {0.f, 0.f, 0.f, 0.f};

    for (int h = 0; h < 4; ++h) {
        __syncthreads();   // prev-head agg done (S,Ht now dead); AL/AR ready (h=0)
        // transpose slice: Ht[k][n] = hs[n][32h+k]
        for (int i = t; i < 4096; i += 1024) {
            int k = i & 31, n = i >> 5;
            Ht[k][n] = (n < NODES) ? hs[n][h * 32 + k] : 0.f;
        }
        __syncthreads();
        // dense Gram: wave -> 32x32 tile, 4x4 per lane, float4 broadcast reads
        {
            float sa[4][4] = {{0.f}};
#pragma unroll
            for (int k = 0; k < 32; ++k) {
                float4 A = *(const float4*)&Ht[k][gi];
                float4 B = *(const float4*)&Ht[k][gj];
                sa[0][0] += A.x*B.x; sa[0][1] += A.x*B.y; sa[0][2] += A.x*B.z; sa[0][3] += A.x*B.w;
                sa[1][0] += A.y*B.x; sa[1][1] += A.y*B.y; sa[1][2] += A.y*B.z; sa[1][3] += A.y*B.w;
                sa[2][0] += A.z*B.x; sa[2][1] += A.z*B.y; sa[2][2] += A.z*B.z; sa[2][3] += A.z*B.w;
                sa[3][0] += A.w*B.x; sa[3][1] += A.w*B.y; sa[3][2] += A.w*B.z; sa[3][3] += A.w*B.w;
            }
#pragma unroll
            for (int ii = 0; ii < 4; ++ii) {
                float4 o; o.x = sa[ii][0]; o.y = sa[ii][1]; o.z = sa[ii][2]; o.w = sa[ii][3];
                *(float4*)&S[gi + ii][gj] = o;
            }
        }
        __syncthreads();
        // dense P = exp(leaky((AL[j]+AR[n]) * sigmoid(S)))
        for (int i = t; i < NODES * 128; i += 1024) {
            int n = i >> 7, j = i & 127;
            float s = S[n][j];
            float sig = 1.f / (1.f + __expf(-s));
            float a = (ALs[h][j] + ARs[h][n]) * sig;
            a = a >= 0.f ? a : 0.2f * a;
            S[n][j] = __expf(a);
        }
        __syncthreads();
        // sparse aggregation: half-wave (32 lanes) per node, P from LDS broadcast
        for (int r = 0; r < 4; ++r) {
            int n = wv * 8 + r * 2 + sslot;
            if (n < NODES) {
                int e0 = row_start[base + n], e1 = row_start[base + n + 1];
                const float* Srow = &S[n][0];
                const float* hcol = &hs[0][h * 32 + c];
                float num = 0.f, den = 0.f;
                int e = e0;
                for (; e + 1 < e1; e += 2) {
                    int s0 = colx[e] - base, s1 = colx[e + 1] - base;
                    float p0 = Srow[s0], p1 = Srow[s1];
                    num += p0 * hcol[s0 * HC]; den += p0;
                    num += p1 * hcol[s1 * HC]; den += p1;
                }
                if (e < e1) {
                    int s0 = colx[e] - base;
                    float p0 = Srow[s0];
                    num += p0 * hcol[s0 * HC]; den += p0;
                }
                acc[r] += num / (den + 1e-16f);
            }
        }
    }

    // ---- epilogue: y + BN partial ----
    float bs = 0.f, bq = 0.f;
    for (int r = 0; r < 4; ++r) {
        int n = wv * 8 + r * 2 + sslot;
        if (n < NODES) {
            float v = 0.25f * acc[r] + bias_s[c];
            y[(size_t)(base + n) * CC + c] = v;
            bs += v; bq += v * v;
        }
    }
    bsum[wv][sslot][c] = bs; bsq[wv][sslot][c] = bq;
    __syncthreads();
    if (t < CC) {
        float Sm = 0.f, Q = 0.f;
        for (int w = 0; w < 16; ++w) {
#pragma unroll
            for (int s2 = 0; s2 < 2; ++s2) { Sm += bsum[w][s2][t]; Q += bsq[w][s2][t]; }
        }
        atomicAdd(&bnacc[t], Sm);
        atomicAdd(&bnacc[CC + t], Q);
    }
}

// BN + relu -> xout; per-graph mean/max pool -> feat[., 124 + l*64 ...]
__global__ void bn_relu_pool(const float* __restrict__ y, const float* __restrict__ acc,
                             const float* __restrict__ gamma, const float* __restrict__ beta,
                             float* __restrict__ xout, float* __restrict__ feat, int l) {
    int g = blockIdx.x;
    int t = threadIdx.x;          // 128
    int c = t & 31, r0 = t >> 5;
    float mu = acc[c] * (1.f / NN);
    float var = acc[32 + c] * (1.f / NN) - mu * mu;
    float sc = rsqrtf(var + 1e-5f) * gamma[c];
    float bt = beta[c];
    float s = 0.f, mx = -INFINITY;
    for (int r = r0; r < NODES; r += 4) {
        int i = (g * NODES + r) * CC + c;
        float v = (y[i] - mu) * sc + bt;
        v = fmaxf(v, 0.f);
        xout[i] = v;
        s += v; mx = fmaxf(mx, v);
    }
    __shared__ float ls[128], lm[128];
    ls[t] = s; lm[t] = mx;
    __syncthreads();
    if (t < 32) {
        float S = ls[t] + ls[32 + t] + ls[64 + t] + ls[96 + t];
        float M = fmaxf(fmaxf(lm[t], lm[32 + t]), fmaxf(lm[64 + t], lm[96 + t]));
        float* fp = feat + g * FEAT_DIM + NODES + l * 64;
        fp[t] = S * (1.f / NODES);
        fp[32 + t] = M;
    }
}

// ---------------- classifier head ----------------
#define L1_GPB 4
#define L1_KS 8
#define L1_KCH 496   // NC / L1_KS = 4 chunks of 124
// grid = (NB/L1_GPB)*L1_KS = 512 blocks, 128 threads
__global__ void lin1_part(const float* __restrict__ X, const float* __restrict__ W,
                          float* __restrict__ part) {
    int ks = blockIdx.x & (L1_KS - 1);
    int gb = (blockIdx.x >> 3) * L1_GPB;
    int t = threadIdx.x;
    int kbeg = ks * L1_KCH;
    __shared__ float xs[L1_GPB][124];
    float acc[L1_GPB] = {0.f, 0.f, 0.f, 0.f};
    for (int k0 = kbeg; k0 < kbeg + L1_KCH; k0 += 124) {
        __syncthreads();
        if (t < 124) {
#pragma unroll
            for (int rr = 0; rr < L1_GPB; ++rr) xs[rr][t] = X[(gb + rr) * NC + k0 + t];
        }
        __syncthreads();
        if (t < 124) {
#pragma unroll 4
            for (int kk = 0; kk < 124; ++kk) {
                float w = W[(k0 + kk) * 124 + t];
#pragma unroll
                for (int rr = 0; rr < L1_GPB; ++rr) acc[rr] += xs[rr][kk] * w;
            }
        }
    }
    if (t < 124)
#pragma unroll
        for (int rr = 0; rr < L1_GPB; ++rr)
            part[(ks * NB + gb + rr) * 124 + t] = acc[rr];
}

__global__ void lin1_reduce(const float* __restrict__ part, const float* __restrict__ b,
                            float* __restrict__ out1) {
    int i = blockIdx.x * blockDim.x + threadIdx.x;
    if (i >= NB * 124) return;
    int j = i % 124;
    float s = b[j];
#pragma unroll
    for (int ks = 0; ks < L1_KS; ++ks) s += part[ks * NB * 124 + i];
    out1[i] = s;
}

// 512 threads: (c = t&127, seg = t>>7 over 4 row-chunks of 64)
__global__ void bn1_relu(const float* __restrict__ out1, const float* __restrict__ gamma,
                         const float* __restrict__ beta, float* __restrict__ feat) {
    __shared__ float ps[4][124], pq[4][124], smu[124], ssc[124], sbt[124];
    int t = threadIdx.x;
    int c = t & 127, seg = t >> 7;
    float s = 0.f, q = 0.f;
    if (c < 124) {
        for (int b = seg * 64; b < seg * 64 + 64; ++b) {
            float v = out1[b * 124 + c]; s += v; q += v * v;
        }
        ps[seg][c] = s; pq[seg][c] = q;
    }
    __syncthreads();
    if (t < 124) {
        float S = ps[0][t] + ps[1][t] + ps[2][t] + ps[3][t];
        float Q = pq[0][t] + pq[1][t] + pq[2][t] + pq[3][t];
        float mu = S * (1.f / NB);
        float var = Q * (1.f / NB) - mu * mu;
        smu[t] = mu; ssc[t] = rsqrtf(var + 1e-5f) * gamma[t]; sbt[t] = beta[t];
    }
    __syncthreads();
    if (c < 124) {
        for (int b = seg * 64; b < seg * 64 + 64; ++b) {
            float v = (out1[b * 124 + c] - smu[c]) * ssc[c] + sbt[c];
            feat[b * FEAT_DIM + c] = fmaxf(v, 0.f);
        }
    }
}

// one block per graph: 320 threads = 40 outputs x 8 K-segments
__global__ void lin2_k(const float* __restrict__ feat, const float* __restrict__ W,
                       const float* __restrict__ b, float* __restrict__ out) {
    __shared__ float psum[8][40];
    int g = blockIdx.x;
    int t = threadIdx.x;
    int j = t % 40, u = t / 40;   // u 0..7
    if (u < 8) {
        int k0 = u * 40, k1 = (u == 7) ? FEAT_DIM : k0 + 40;   // last seg: 36 extra
        float s = 0.f;
        for (int k = k0; k < k1; ++k) s += feat[g * FEAT_DIM + k] * W[k * NCLS + j];
        psum[u][j] = s;
    }
    __syncthreads();
    if (t < NCLS) {
        float s = b[t];
#pragma unroll
        for (int u2 = 0; u2 < 8; ++u2) s += psum[u2][t];
        out[g * NCLS + t] = s;
    }
}

extern "C" void kernel_launch(void* const* d_in, const int* in_sizes, int n_in,
                              void* d_out, int out_size, void* d_ws, size_t ws_size,
                              hipStream_t stream) {
    const float* x      = (const float*)d_in[0];
    const int*   ei     = (const int*)d_in[1];
    const float* conv_W = (const float*)d_in[3];
    const float* att_l  = (const float*)d_in[4];
    const float* att_r  = (const float*)d_in[5];
    const float* conv_b = (const float*)d_in[6];
    const float* bn_g   = (const float*)d_in[7];
    const float* bn_b   = (const float*)d_in[8];
    const float* lin1_W = (const float*)d_in[9];
    const float* lin1_b = (const float*)d_in[10];
    const float* bn1_g  = (const float*)d_in[11];
    const float* bn1_b  = (const float*)d_in[12];
    const float* lin2_W = (const float*)d_in[13];
    const float* lin2_b = (const float*)d_in[14];

    float* ws = (float*)d_ws;
    float* y     = ws;                         // NN*32
    float* xbuf  = y + (size_t)NN * CC;        // NN*32
    float* bnacc = xbuf + (size_t)NN * CC;     // 64
    float* feat  = bnacc + 64;                 // NB*316
    float* out1  = feat + NB * FEAT_DIM;       // NB*124
    float* part  = out1 + NB * 124;            // 8*NB*124
    int* deg       = (int*)(part + L1_KS * NB * 124);
    int* row_start = deg + NN;
    int* cursor    = row_start + NN + 1;
    int* colx      = cursor + NN;

    // CSR build
    init_deg<<<(NN + 255) / 256, 256, 0, stream>>>(deg);
    count_deg<<<(NE + 255) / 256, 256, 0, stream>>>(ei, deg);
    scan_k<<<1, 1024, 0, stream>>>(deg, row_start);
    fill_self<<<(NN + 255) / 256, 256, 0, stream>>>(row_start, cursor, colx);
    fill_edges<<<(NE + 255) / 256, 256, 0, stream>>>(ei, row_start, cursor, colx);

    const float* xin = x;
    for (int l = 0; l < 3; ++l) {
        hipMemsetAsync(bnacc, 0, 64 * sizeof(float), stream);
        conv_graph<<<NB, 1024, 0, stream>>>(xin, conv_W + l * CC * HC,
                                            att_l + l * HC, att_r + l * HC,
                                            conv_b + l * CC, row_start, colx, y, bnacc);
        bn_relu_pool<<<NB, 128, 0, stream>>>(y, bnacc, bn_g + l * CC, bn_b + l * CC,
                                             xbuf, feat, l);
        xin = xbuf;
    }

    lin1_part<<<(NB / L1_GPB) * L1_KS, 128, 0, stream>>>(xbuf, lin1_W, part);
    lin1_reduce<<<(NB * 124 + 255) / 256, 256, 0, stream>>>(part, lin1_b, out1);
    bn1_relu<<<1, 512, 0, stream>>>(out1, bn1_g, bn1_b, feat);
    lin2_k<<<NB, 320, 0, stream>>>(feat, lin2_W, lin2_b, (float*)d_out);
}

// Round 6
// 282.086 us; speedup vs baseline: 2.8156x; 1.4310x over previous
//
#include <hip/hip_runtime.h>
#include <math.h>

#define NN 31744        // total nodes B*NODES
#define NE 507904       // input edges (no self loops)
#define NODES 124
#define NB 256          // graphs
#define CC 32           // channels
#define HC 128          // H*C
#define FEAT_DIM 316
#define NCLS 40
#define NC 3968         // NODES*CC

typedef __attribute__((ext_vector_type(8))) short bf16x8;
typedef __attribute__((ext_vector_type(4))) float f32x4;

__device__ __forceinline__ unsigned short f2bf(float f) {
    unsigned u = __float_as_uint(f);
    u = u + 0x7FFFu + ((u >> 16) & 1u);      // RNE
    return (unsigned short)(u >> 16);
}
__device__ __forceinline__ float bf2f(unsigned short s) {
    return __uint_as_float(((unsigned)s) << 16);
}

// ---------------- CSR build ----------------
__global__ void init_deg(int* deg) {
    int i = blockIdx.x * blockDim.x + threadIdx.x;
    if (i < NN) deg[i] = 1;  // self loop
}

__global__ void count_deg(const int* __restrict__ ei, int* deg) {
    int e = blockIdx.x * blockDim.x + threadIdx.x;
    if (e < NE) atomicAdd(&deg[ei[NE + e]], 1);
}

__global__ void scan_k(const int* __restrict__ deg, int* __restrict__ row_start) {
    int t = threadIdx.x;             // 1024 threads, NN = 1024*31
    int base = t * 31;
    int s = 0;
    for (int k = 0; k < 31; ++k) s += deg[base + k];
    __shared__ int part[1024];
    part[t] = s;
    __syncthreads();
    for (int off = 1; off < 1024; off <<= 1) {
        int u = (t >= off) ? part[t - off] : 0;
        __syncthreads();
        part[t] += u;
        __syncthreads();
    }
    int pre = part[t] - s;           // exclusive prefix for this chunk
    for (int k = 0; k < 31; ++k) { row_start[base + k] = pre; pre += deg[base + k]; }
    if (t == 1023) row_start[NN] = part[1023];
}

__global__ void fill_self(const int* __restrict__ row_start, int* cursor, int* colx) {
    int i = blockIdx.x * blockDim.x + threadIdx.x;
    if (i < NN) { cursor[i] = 1; colx[row_start[i]] = i; }
}

__global__ void fill_edges(const int* __restrict__ ei, const int* __restrict__ row_start,
                           int* cursor, int* colx) {
    int e = blockIdx.x * blockDim.x + threadIdx.x;
    if (e < NE) {
        int s = ei[e], d = ei[NE + e];
        int p = atomicAdd(&cursor[d], 1);
        colx[row_start[d] + p] = s;
    }
}

// ---------------- fused per-graph layer kernel (MFMA, split-precision, dup-aware) ----
#define HS 136   // h plane row stride in shorts (272B -> every frag 16B-aligned)
#define PS 136   // P plane row stride
#define TS 136   // hT row stride
#define EXCAP 240

__global__ __launch_bounds__(1024, 1) void conv_graph(
    const float* __restrict__ xin, const float* __restrict__ W,
    const float* __restrict__ attl, const float* __restrict__ attr,
    const float* __restrict__ bias,
    const int* __restrict__ row_start, const int* __restrict__ colx,
    float* __restrict__ y, float* __restrict__ bnacc) {

    __shared__ short hbh[128 * HS];        // h bf16 hi plane [node][ch]
    __shared__ short hbl[128 * HS];        // h bf16 lo plane
    __shared__ short hT[32 * TS];          // per-head h^T hi plane [ch][node]
    __shared__ short Pmh[128 * PS];        // P hi [dst][src]; xs / yout overlays
    __shared__ short Pml[128 * PS];        // P lo; fp32 W overlay early
    __shared__ float ALs[4][128], ARs[4][128];
    __shared__ float alw[128], arw[128];
    __shared__ unsigned mask[128][4];
    __shared__ unsigned ex[EXCAP];         // (dst<<16)|(src<<8)|count for duplicated edges
    __shared__ int nex;
    __shared__ float den[128];
    __shared__ float bias_s[32];
    __shared__ float bsum[16][32], bsq[16][32];

    int g = blockIdx.x, t = threadIdx.x, base = g * NODES;
    float* xs = (float*)Pmh;               // [124][32] overlay
    float* Wf = (float*)Pml;               // [32][128] overlay

    // ---- stage ----
    {
        const float4* s = (const float4*)(xin + (size_t)base * CC);
        float4* d = (float4*)xs;
        for (int i = t; i < NODES * CC / 4; i += 1024) d[i] = s[i];
    }
    for (int i = t; i < CC * HC; i += 1024) Wf[i] = W[i];
    if (t < HC) { alw[t] = attl[t]; arw[t] = attr[t]; }
    if (t < CC) bias_s[t] = bias[t];
    if (t == 0) nex = 0;
    __syncthreads();

    // ---- H = x@W -> hi/lo bf16 planes ----
    {
        int hc = t & 127, n0 = t >> 7;
        float wreg[CC];
#pragma unroll
        for (int k = 0; k < CC; ++k) wreg[k] = Wf[k * HC + hc];
        for (int n = n0; n < NODES; n += 8) {
            const float4* xr = (const float4*)&xs[n * CC];
            float s = 0.f;
#pragma unroll
            for (int q = 0; q < 8; ++q) {
                float4 a = xr[q];
                s += a.x * wreg[4*q] + a.y * wreg[4*q+1] + a.z * wreg[4*q+2] + a.w * wreg[4*q+3];
            }
            unsigned short hi = f2bf(s);
            unsigned short lo = f2bf(s - bf2f(hi));
            hbh[n * HS + hc] = (short)hi;
            hbl[n * HS + hc] = (short)lo;
        }
    }
    if (t < 4 * HS) { hbh[124 * HS + t] = 0; hbl[124 * HS + t] = 0; }  // pad rows
    __syncthreads();

    // ---- AL/AR (fp32 from hi+lo), edge mask + duplicate extraction ----
    if (t < 512) {
        int n = t >> 2, hh = t & 3;
        float a = 0.f, b = 0.f;
        if (n < NODES) {
#pragma unroll
            for (int k = 0; k < CC; ++k) {
                float v = bf2f((unsigned short)hbh[n * HS + hh * 32 + k])
                        + bf2f((unsigned short)hbl[n * HS + hh * 32 + k]);
                a += v * alw[hh * 32 + k];
                b += v * arw[hh * 32 + k];
            }
        }
        ALs[hh][n] = a; ARs[hh][n] = b;
    }
    if (t < 128) { mask[t][0] = 0u; mask[t][1] = 0u; mask[t][2] = 0u; mask[t][3] = 0u; }
    if (t < NODES) {
        int e0 = row_start[base + t], e1 = row_start[base + t + 1];
        unsigned m0 = 0, m1 = 0, m2 = 0, m3 = 0;
        int dup_s[8], dup_c[8], nd = 0;
        for (int e = e0; e < e1; ++e) {
            int s = colx[e] - base;
            unsigned* mp = (s < 64) ? ((s < 32) ? &m0 : &m1) : ((s < 96) ? &m2 : &m3);
            unsigned b = 1u << (s & 31);
            if (*mp & b) {                      // duplicated edge
                int j = 0;
                for (; j < nd; ++j) if (dup_s[j] == s) { dup_c[j]++; break; }
                if (j == nd && nd < 8) { dup_s[nd] = s; dup_c[nd] = 2; nd++; }
            } else *mp |= b;
        }
        mask[t][0] = m0; mask[t][1] = m1; mask[t][2] = m2; mask[t][3] = m3;
        if (nd) {
            int slot = atomicAdd(&nex, nd);
            for (int j = 0; j < nd; ++j)
                if (slot + j < EXCAP)
                    ex[slot + j] = ((unsigned)t << 16) | ((unsigned)dup_s[j] << 8)
                                 | (unsigned)dup_c[j];
        }
    }

    // ---- per-head: hT || Gram(3xMFMA)->P(hi/lo) -> dup-scale -> den + PV(2xMFMA) ----
    int wv = t >> 6, l = t & 63;
    int l15 = l & 15, l4 = l >> 4;
    int DI = wv >> 1, CJ = wv & 1;            // PV job: dst-tile, ch-tile
    f32x4 accf = {0.f, 0.f, 0.f, 0.f};

    for (int hh = 0; hh < 4; ++hh) {
        __syncthreads();          // prev PV done (Pm*/hT free); ALs/mask/ex ready (hh=0)
        // per-head transposed slice (hi plane)
        for (int i = t; i < 4096; i += 1024) {
            int n = i & 127, k = i >> 7;
            hT[k * TS + n] = hbh[n * HS + hh * 32 + k];
        }
#pragma unroll
        for (int j = 0; j < 4; ++j) {
            int idx = wv * 4 + j;             // 64 Gram tiles
            int SI = idx >> 3, DJ = idx & 7;
            int ao = (SI * 16 + l15) * HS + hh * 32 + l4 * 8;
            int bo = (DJ * 16 + l15) * HS + hh * 32 + l4 * 8;
            bf16x8 ah = *(bf16x8*)&hbh[ao];
            bf16x8 al_ = *(bf16x8*)&hbl[ao];
            bf16x8 bh = *(bf16x8*)&hbh[bo];
            bf16x8 bl_ = *(bf16x8*)&hbl[bo];
            f32x4 c = {0.f, 0.f, 0.f, 0.f};
            c = __builtin_amdgcn_mfma_f32_16x16x32_bf16(ah, bh, c, 0, 0, 0);
            c = __builtin_amdgcn_mfma_f32_16x16x32_bf16(ah, bl_, c, 0, 0, 0);
            c = __builtin_amdgcn_mfma_f32_16x16x32_bf16(al_, bh, c, 0, 0, 0);
            int src0 = SI * 16 + l4 * 4;
            int dst  = DJ * 16 + l15;
            float4 al4 = *(float4*)&ALs[hh][src0];
            float ar = ARs[hh][dst];
            unsigned mw = mask[dst][src0 >> 5] >> (src0 & 31);
            unsigned short ph[4], pl[4];
#pragma unroll
            for (int r = 0; r < 4; ++r) {
                float lg = c[r];
                float sig = __builtin_amdgcn_rcpf(1.f + __expf(-lg));
                float a2 = (((const float*)&al4)[r] + ar) * sig;
                a2 = a2 >= 0.f ? a2 : 0.2f * a2;
                float pv = ((mw >> r) & 1u) ? __expf(a2) : 0.f;
                ph[r] = f2bf(pv);
                pl[r] = f2bf(pv - bf2f(ph[r]));
            }
            uint2 pk, ql;
            pk.x = ((unsigned)ph[1] << 16) | ph[0];
            pk.y = ((unsigned)ph[3] << 16) | ph[2];
            ql.x = ((unsigned)pl[1] << 16) | pl[0];
            ql.y = ((unsigned)pl[3] << 16) | pl[2];
            *(uint2*)&Pmh[dst * PS + src0] = pk;
            *(uint2*)&Pml[dst * PS + src0] = ql;
        }
        __syncthreads();                      // P written
        // duplicate-edge multiplicity: P[dst][src] *= count
        {
            int ne = nex < EXCAP ? nex : EXCAP;
            if (t < ne) {
                unsigned E = ex[t];
                int off = (int)(E >> 16) * PS + (int)((E >> 8) & 255u);
                float v = (bf2f((unsigned short)Pmh[off]) + bf2f((unsigned short)Pml[off]))
                        * (float)(E & 255u);
                unsigned short hi = f2bf(v);
                Pmh[off] = (short)hi;
                Pml[off] = (short)f2bf(v - bf2f(hi));
            }
        }
        __syncthreads();                      // P final; hT ready
        if (t < 128) {                        // den row-sums over both planes
            float s = 0.f;
            for (int kb = 0; kb < 16; ++kb) {
                bf16x8 p = *(bf16x8*)&Pmh[t * PS + kb * 8];
                bf16x8 q = *(bf16x8*)&Pml[t * PS + kb * 8];
#pragma unroll
                for (int e2 = 0; e2 < 8; ++e2)
                    s += bf2f((unsigned short)p[e2]) + bf2f((unsigned short)q[e2]);
            }
            den[t] = s;
        }
        f32x4 num = {0.f, 0.f, 0.f, 0.f};
#pragma unroll
        for (int kb = 0; kb < 4; ++kb) {
            int aoff = (DI * 16 + l15) * PS + kb * 32 + l4 * 8;
            bf16x8 ah = *(bf16x8*)&Pmh[aoff];
            bf16x8 al_ = *(bf16x8*)&Pml[aoff];
            bf16x8 b = *(bf16x8*)&hT[(CJ * 16 + l15) * TS + kb * 32 + l4 * 8];
            num = __builtin_amdgcn_mfma_f32_16x16x32_bf16(ah, b, num, 0, 0, 0);
            num = __builtin_amdgcn_mfma_f32_16x16x32_bf16(al_, b, num, 0, 0, 0);
        }
        __syncthreads();                      // den ready (P/hT reads done)
        float4 dn = *(float4*)&den[DI * 16 + l4 * 4];
#pragma unroll
        for (int r = 0; r < 4; ++r)
            ((float*)&accf)[r] += ((float*)&num)[r] / (((const float*)&dn)[r] + 1e-16f);
    }

    // ---- epilogue: head mean + bias -> yout -> y + BN partials ----
    __syncthreads();
    float* yout = (float*)Pmh;                // [124][33]
    {
        int c = CJ * 16 + l15;
#pragma unroll
        for (int r = 0; r < 4; ++r) {
            int n = DI * 16 + l4 * 4 + r;
            if (n < NODES) yout[n * 33 + c] = 0.25f * ((float*)&accf)[r] + bias_s[c];
        }
    }
    __syncthreads();
    if (t < 512) {
        int c = t & 31, r0 = t >> 5;          // 16 row-groups
        float s = 0.f, q = 0.f;
        for (int n = r0; n < NODES; n += 16) {
            float v = yout[n * 33 + c];
            y[(size_t)(base + n) * CC + c] = v;
            s += v; q += v * v;
        }
        bsum[r0][c] = s; bsq[r0][c] = q;
    }
    __syncthreads();
    if (t < CC) {
        float S = 0.f, Q = 0.f;
        for (int w = 0; w < 16; ++w) { S += bsum[w][t]; Q += bsq[w][t]; }
        atomicAdd(&bnacc[t], S);
        atomicAdd(&bnacc[CC + t], Q);
    }
}

// BN + relu -> xout; per-graph mean/max pool -> feat[., 124 + l*64 ...]
__global__ void bn_relu_pool(const float* __restrict__ y, const float* __restrict__ acc,
                             const float* __restrict__ gamma, const float* __restrict__ beta,
                             float* __restrict__ xout, float* __restrict__ feat, int l) {
    int g = blockIdx.x;
    int t = threadIdx.x;          // 128
    int c = t & 31, r0 = t >> 5;
    float mu = acc[c] * (1.f / NN);
    float var = acc[32 + c] * (1.f / NN) - mu * mu;
    float sc = rsqrtf(var + 1e-5f) * gamma[c];
    float bt = beta[c];
    float s = 0.f, mx = -INFINITY;
    for (int r = r0; r < NODES; r += 4) {
        int i = (g * NODES + r) * CC + c;
        float v = (y[i] - mu) * sc + bt;
        v = fmaxf(v, 0.f);
        xout[i] = v;
        s += v; mx = fmaxf(mx, v);
    }
    __shared__ float ls[128], lm[128];
    ls[t] = s; lm[t] = mx;
    __syncthreads();
    if (t < 32) {
        float S = ls[t] + ls[32 + t] + ls[64 + t] + ls[96 + t];
        float M = fmaxf(fmaxf(lm[t], lm[32 + t]), fmaxf(lm[64 + t], lm[96 + t]));
        float* fp = feat + g * FEAT_DIM + NODES + l * 64;
        fp[t] = S * (1.f / NODES);
        fp[32 + t] = M;
    }
}

// ---------------- classifier head ----------------
#define L1_GPB 4
#define L1_KS 16
#define L1_KCH 248   // NC / L1_KS = 2 chunks of 124
// grid = (NB/L1_GPB)*L1_KS = 1024 blocks, 128 threads
__global__ void lin1_part(const float* __restrict__ X, const float* __restrict__ W,
                          float* __restrict__ part) {
    int ks = blockIdx.x & (L1_KS - 1);
    int gb = (blockIdx.x >> 4) * L1_GPB;
    int t = threadIdx.x;
    int kbeg = ks * L1_KCH;
    __shared__ float xs[L1_GPB][124];
    float acc[L1_GPB] = {0.f, 0.f, 0.f, 0.f};
    for (int k0 = kbeg; k0 < kbeg + L1_KCH; k0 += 124) {
        __syncthreads();
        if (t < 124) {
#pragma unroll
            for (int rr = 0; rr < L1_GPB; ++rr) xs[rr][t] = X[(gb + rr) * NC + k0 + t];
        }
        __syncthreads();
        if (t < 124) {
#pragma unroll 4
            for (int kk = 0; kk < 124; ++kk) {
                float w = W[(k0 + kk) * 124 + t];
#pragma unroll
                for (int rr = 0; rr < L1_GPB; ++rr) acc[rr] += xs[rr][kk] * w;
            }
        }
    }
    if (t < 124)
#pragma unroll
        for (int rr = 0; rr < L1_GPB; ++rr)
            part[(ks * NB + gb + rr) * 124 + t] = acc[rr];
}

__global__ void lin1_reduce(const float* __restrict__ part, const float* __restrict__ b,
                            float* __restrict__ out1) {
    int i = blockIdx.x * blockDim.x + threadIdx.x;
    if (i >= NB * 124) return;
    int j = i % 124;
    float s = b[j];
#pragma unroll
    for (int ks = 0; ks < L1_KS; ++ks) s += part[ks * NB * 124 + i];
    out1[i] = s;
}

// 512 threads: (c = t&127, seg = t>>7 over 4 row-chunks of 64)
__global__ void bn1_relu(const float* __restrict__ out1, const float* __restrict__ gamma,
                         const float* __restrict__ beta, float* __restrict__ feat) {
    __shared__ float ps[4][124], pq[4][124], smu[124], ssc[124], sbt[124];
    int t = threadIdx.x;
    int c = t & 127, seg = t >> 7;
    float s = 0.f, q = 0.f;
    if (c < 124) {
        for (int b = seg * 64; b < seg * 64 + 64; ++b) {
            float v = out1[b * 124 + c]; s += v; q += v * v;
        }
        ps[seg][c] = s; pq[seg][c] = q;
    }
    __syncthreads();
    if (t < 124) {
        float S = ps[0][t] + ps[1][t] + ps[2][t] + ps[3][t];
        float Q = pq[0][t] + pq[1][t] + pq[2][t] + pq[3][t];
        float mu = S * (1.f / NB);
        float var = Q * (1.f / NB) - mu * mu;
        smu[t] = mu; ssc[t] = rsqrtf(var + 1e-5f) * gamma[t]; sbt[t] = beta[t];
    }
    __syncthreads();
    if (c < 124) {
        for (int b = seg * 64; b < seg * 64 + 64; ++b) {
            float v = (out1[b * 124 + c] - smu[c]) * ssc[c] + sbt[c];
            feat[b * FEAT_DIM + c] = fmaxf(v, 0.f);
        }
    }
}

// one block per graph: 320 threads = 40 outputs x 8 K-segments
__global__ void lin2_k(const float* __restrict__ feat, const float* __restrict__ W,
                       const float* __restrict__ b, float* __restrict__ out) {
    __shared__ float psum[8][40];
    int g = blockIdx.x;
    int t = threadIdx.x;
    int j = t % 40, u = t / 40;   // u 0..7
    if (u < 8) {
        int k0 = u * 40, k1 = (u == 7) ? FEAT_DIM : k0 + 40;   // last seg: 36 extra
        float s = 0.f;
        for (int k = k0; k < k1; ++k) s += feat[g * FEAT_DIM + k] * W[k * NCLS + j];
        psum[u][j] = s;
    }
    __syncthreads();
    if (t < NCLS) {
        float s = b[t];
#pragma unroll
        for (int u2 = 0; u2 < 8; ++u2) s += psum[u2][t];
        out[g * NCLS + t] = s;
    }
}

extern "C" void kernel_launch(void* const* d_in, const int* in_sizes, int n_in,
                              void* d_out, int out_size, void* d_ws, size_t ws_size,
                              hipStream_t stream) {
    const float* x      = (const float*)d_in[0];
    const int*   ei     = (const int*)d_in[1];
    const float* conv_W = (const float*)d_in[3];
    const float* att_l  = (const float*)d_in[4];
    const float* att_r  = (const float*)d_in[5];
    const float* conv_b = (const float*)d_in[6];
    const float* bn_g   = (const float*)d_in[7];
    const float* bn_b   = (const float*)d_in[8];
    const float* lin1_W = (const float*)d_in[9];
    const float* lin1_b = (const float*)d_in[10];
    const float* bn1_g  = (const float*)d_in[11];
    const float* bn1_b  = (const float*)d_in[12];
    const float* lin2_W = (const float*)d_in[13];
    const float* lin2_b = (const float*)d_in[14];

    float* ws = (float*)d_ws;
    float* y     = ws;                         // NN*32
    float* xbuf  = y + (size_t)NN * CC;        // NN*32
    float* bnacc = xbuf + (size_t)NN * CC;     // 64
    float* feat  = bnacc + 64;                 // NB*316
    float* out1  = feat + NB * FEAT_DIM;       // NB*124
    float* part  = out1 + NB * 124;            // 16*NB*124
    int* deg       = (int*)(part + L1_KS * NB * 124);
    int* row_start = deg + NN;
    int* cursor    = row_start + NN + 1;
    int* colx      = cursor + NN;

    // CSR build
    init_deg<<<(NN + 255) / 256, 256, 0, stream>>>(deg);
    count_deg<<<(NE + 255) / 256, 256, 0, stream>>>(ei, deg);
    scan_k<<<1, 1024, 0, stream>>>(deg, row_start);
    fill_self<<<(NN + 255) / 256, 256, 0, stream>>>(row_start, cursor, colx);
    fill_edges<<<(NE + 255) / 256, 256, 0, stream>>>(ei, row_start, cursor, colx);

    const float* xin = x;
    for (int l = 0; l < 3; ++l) {
        hipMemsetAsync(bnacc, 0, 64 * sizeof(float), stream);
        conv_graph<<<NB, 1024, 0, stream>>>(xin, conv_W + l * CC * HC,
                                            att_l + l * HC, att_r + l * HC,
                                            conv_b + l * CC, row_start, colx, y, bnacc);
        bn_relu_pool<<<NB, 128, 0, stream>>>(y, bnacc, bn_g + l * CC, bn_b + l * CC,
                                             xbuf, feat, l);
        xin = xbuf;
    }

    lin1_part<<<(NB / L1_GPB) * L1_KS, 128, 0, stream>>>(xbuf, lin1_W, part);
    lin1_reduce<<<(NB * 124 + 255) / 256, 256, 0, stream>>>(part, lin1_b, out1);
    bn1_relu<<<1, 512, 0, stream>>>(out1, bn1_g, bn1_b, feat);
    lin2_k<<<NB, 320, 0, stream>>>(feat, lin2_W, lin2_b, (float*)d_out);
}

// Round 7
// 212.195 us; speedup vs baseline: 3.7430x; 1.3294x over previous
//
#include <hip/hip_runtime.h>
#include <math.h>

#define NN 31744        // total nodes B*NODES
#define NE 507904       // input edges (no self loops)
#define EP 1984         // edges per graph
#define NODES 124
#define NB 256          // graphs
#define CC 32           // channels
#define HC 128          // H*C
#define FEAT_DIM 316
#define NCLS 40
#define NC 3968         // NODES*CC
#define EXCAP 192

typedef __attribute__((ext_vector_type(8))) short bf16x8;
typedef __attribute__((ext_vector_type(4))) float f32x4;

__device__ __forceinline__ unsigned short f2bf(float f) {
    unsigned u = __float_as_uint(f);
    u = u + 0x7FFFu + ((u >> 16) & 1u);      // RNE
    return (unsigned short)(u >> 16);
}
__device__ __forceinline__ float bf2f(unsigned short s) {
    return __uint_as_float(((unsigned)s) << 16);
}

// ---------------- per-graph mask + duplicate-edge build (layer-invariant) -------------
// one block per graph; dense count matrix in LDS; dup entries sorted by dst.
__global__ __launch_bounds__(256) void mask_build(const int* __restrict__ ei,
                                                  unsigned* __restrict__ gmask,
                                                  int* __restrict__ gdst,
                                                  int* __restrict__ gdent) {
    __shared__ unsigned mcnt[NODES * NODES];   // 61.5 KB
    __shared__ int cnt[128], pref[128];
    __shared__ int locs[124][8];
    int g = blockIdx.x, t = threadIdx.x;
    for (int i = t; i < NODES * NODES; i += 256) mcnt[i] = 0u;
    __syncthreads();
    for (int e = t; e < EP; e += 256) {
        int s = ei[g * EP + e] - g * NODES;
        int d = ei[NE + g * EP + e] - g * NODES;
        atomicAdd(&mcnt[d * NODES + s], 1u);
    }
    __syncthreads();
    int nd = 0;
    if (t < 124) {
        unsigned m[4] = {0u, 0u, 0u, 0u};
        for (int s = 0; s < NODES; ++s) {
            unsigned c = mcnt[t * NODES + s] + (s == t ? 1u : 0u);   // self loop
            if (c) {
                m[s >> 5] |= 1u << (s & 31);
                if (c > 1u && nd < 8) { locs[t][nd] = (s << 8) | (int)c; nd++; }
            }
        }
        uint4 mm; mm.x = m[0]; mm.y = m[1]; mm.z = m[2]; mm.w = m[3];
        *(uint4*)&gmask[(size_t)(g * NODES + t) * 4] = mm;
        cnt[t] = nd;
    } else if (t < 128) cnt[t] = 0;
    __syncthreads();
    if (t < 128) pref[t] = cnt[t];
    __syncthreads();
    for (int off = 1; off < 128; off <<= 1) {
        int v = (t >= off && t < 128) ? pref[t - off] : 0;
        __syncthreads();
        if (t < 128) pref[t] += v;
        __syncthreads();
    }
    if (t < 124) {
        int off = pref[t] - cnt[t];
        gdst[g * 132 + t] = off < EXCAP ? off : EXCAP;
        for (int j = 0; j < nd; ++j)
            if (off + j < EXCAP) gdent[g * EXCAP + off + j] = locs[t][j];
    }
    if (t == 0) {
        int tot = pref[127];
        gdst[g * 132 + 124] = tot < EXCAP ? tot : EXCAP;
    }
}

// ---------------- fused per-graph layer kernel (MFMA everywhere) ----------------
#define HS 136   // h plane row stride in shorts
#define PS 136   // P plane row stride
#define TS 136   // hT row stride
#define XS 40    // x / WT staging stride in shorts

__global__ __launch_bounds__(1024, 1) void conv_graph(
    const float* __restrict__ xin, const float* __restrict__ W,
    const float* __restrict__ attl, const float* __restrict__ attr,
    const float* __restrict__ bias,
    const unsigned* __restrict__ gmask, const int* __restrict__ gdst,
    const int* __restrict__ gdent,
    float* __restrict__ y, float* __restrict__ bnacc) {

    __shared__ short hbh[128 * HS];        // h bf16 hi plane [node][ch]
    __shared__ short hbl[128 * HS];        // h bf16 lo plane
    __shared__ short Pm2[2 * 128 * PS];    // P hi/lo; x/WT staging + yout overlays
    __shared__ short hT[32 * TS];          // per-head h^T hi plane [ch][node]
    __shared__ float ALs[4][128], ARs[4][128];
    __shared__ float alw[128], arw[128];
    __shared__ unsigned mask[128][4];
    __shared__ int dupst[132];
    __shared__ int dupent[EXCAP];
    __shared__ float den[128];
    __shared__ float bias_s[32];
    __shared__ float bsum[8][32], bsq[8][32];

    int g = blockIdx.x, t = threadIdx.x, base = g * NODES;
    short* Pmh = Pm2;
    short* Pml = Pm2 + 128 * PS;
    short* xh  = Pm2;                     // [128][XS] overlay (dead after H)
    short* xl  = Pm2 + 5120;
    short* WTh = Pm2 + 10240;             // [128][XS]
    short* WTl = Pm2 + 15360;

    // ---- stage: x -> hi/lo, W^T -> hi/lo, consts, mask, dup lists ----
    {
        const float4* xsrc = (const float4*)(xin + (size_t)base * CC);
        for (int i = t; i < 992; i += 1024) {       // 124*32/4
            float4 v = xsrc[i];
            int n = i >> 3, c4 = i & 7;
            unsigned short h0 = f2bf(v.x), h1 = f2bf(v.y), h2 = f2bf(v.z), h3 = f2bf(v.w);
            unsigned short l0 = f2bf(v.x - bf2f(h0)), l1 = f2bf(v.y - bf2f(h1));
            unsigned short l2 = f2bf(v.z - bf2f(h2)), l3 = f2bf(v.w - bf2f(h3));
            uint2 ph; ph.x = ((unsigned)h1 << 16) | h0; ph.y = ((unsigned)h3 << 16) | h2;
            uint2 pl; pl.x = ((unsigned)l1 << 16) | l0; pl.y = ((unsigned)l3 << 16) | l2;
            *(uint2*)&xh[n * XS + c4 * 4] = ph;
            *(uint2*)&xl[n * XS + c4 * 4] = pl;
        }
        if (t < 4 * XS) { xh[124 * XS + t] = 0; xl[124 * XS + t] = 0; }   // zero pad rows
    }
    {
        int hc = t & 127, mq = t >> 7;              // mq 0..7 -> k chunk of 4
        int ks = mq * 4;
        unsigned short hh4[4], ll4[4];
#pragma unroll
        for (int q = 0; q < 4; ++q) {
            float w = W[(ks + q) * HC + hc];
            hh4[q] = f2bf(w);
            ll4[q] = f2bf(w - bf2f(hh4[q]));
        }
        uint2 ph; ph.x = ((unsigned)hh4[1] << 16) | hh4[0]; ph.y = ((unsigned)hh4[3] << 16) | hh4[2];
        uint2 pl; pl.x = ((unsigned)ll4[1] << 16) | ll4[0]; pl.y = ((unsigned)ll4[3] << 16) | ll4[2];
        *(uint2*)&WTh[hc * XS + ks] = ph;
        *(uint2*)&WTl[hc * XS + ks] = pl;
    }
    if (t < HC) { alw[t] = attl[t]; arw[t] = attr[t]; }
    if (t < CC) bias_s[t] = bias[t];
    if (t < 128) {
        if (t < 124) {
            uint4 m = *(const uint4*)&gmask[(size_t)(base + t) * 4];
            mask[t][0] = m.x; mask[t][1] = m.y; mask[t][2] = m.z; mask[t][3] = m.w;
        } else { mask[t][0] = 0u; mask[t][1] = 0u; mask[t][2] = 0u; mask[t][3] = 0u; }
    }
    if (t < 132) dupst[t] = gdst[g * 132 + (t < 124 ? t : 124)];
    if (t >= 832 && t < 832 + EXCAP) dupent[t - 832] = gdent[g * EXCAP + (t - 832)];
    __syncthreads();

    int wv = t >> 6, l = t & 63;
    int l15 = l & 15, l4 = l >> 4;

    // ---- H = x@W via split MFMA: 64 tiles, 4 per wave ----
#pragma unroll
    for (int j = 0; j < 4; ++j) {
        int idx = wv * 4 + j;
        int tr = idx >> 3, tc = idx & 7;
        bf16x8 ah = *(bf16x8*)&xh[(tr * 16 + l15) * XS + l4 * 8];
        bf16x8 al_ = *(bf16x8*)&xl[(tr * 16 + l15) * XS + l4 * 8];
        bf16x8 bh = *(bf16x8*)&WTh[(tc * 16 + l15) * XS + l4 * 8];
        bf16x8 bl_ = *(bf16x8*)&WTl[(tc * 16 + l15) * XS + l4 * 8];
        f32x4 c = {0.f, 0.f, 0.f, 0.f};
        c = __builtin_amdgcn_mfma_f32_16x16x32_bf16(ah, bh, c, 0, 0, 0);
        c = __builtin_amdgcn_mfma_f32_16x16x32_bf16(ah, bl_, c, 0, 0, 0);
        c = __builtin_amdgcn_mfma_f32_16x16x32_bf16(al_, bh, c, 0, 0, 0);
        int hc = tc * 16 + l15;
#pragma unroll
        for (int r = 0; r < 4; ++r) {
            int n = tr * 16 + l4 * 4 + r;
            float s = c[r];
            unsigned short hi = f2bf(s);
            hbh[n * HS + hc] = (short)hi;
            hbl[n * HS + hc] = (short)f2bf(s - bf2f(hi));
        }
    }
    __syncthreads();                       // h ready (x/WT overlays now dead)

    // ---- AL/AR: conflict-free b128 row reads ----
    if (t < 512) {
        int w = t >> 6, ln = t & 63;
        int hh = w >> 1, n = ((w & 1) << 6) + ln;
        float a = 0.f, b = 0.f;
#pragma unroll
        for (int q = 0; q < 4; ++q) {
            bf16x8 H = *(bf16x8*)&hbh[n * HS + hh * 32 + q * 8];
            bf16x8 L = *(bf16x8*)&hbl[n * HS + hh * 32 + q * 8];
#pragma unroll
            for (int e = 0; e < 8; ++e) {
                float v = bf2f((unsigned short)H[e]) + bf2f((unsigned short)L[e]);
                a += v * alw[hh * 32 + q * 8 + e];
                b += v * arw[hh * 32 + q * 8 + e];
            }
        }
        ALs[hh][n] = a; ARs[hh][n] = b;
    }

    // ---- per-head: [transpose || Gram+P(dup-scaled)] -> barrier -> [den || PV] ----
    int DI = wv >> 1, CJ = wv & 1;         // PV job: dst-tile, ch-tile
    f32x4 accf = {0.f, 0.f, 0.f, 0.f};
    f32x4 num = {0.f, 0.f, 0.f, 0.f};

    for (int hh = 0; hh < 4; ++hh) {
        __syncthreads();                   // hT/Pm free; ALs ready; den(prev) stable
        if (hh > 0) {                      // divide for previous head
            float4 dn = *(float4*)&den[DI * 16 + l4 * 4];
#pragma unroll
            for (int r = 0; r < 4; ++r)
                ((float*)&accf)[r] += ((float*)&num)[r] / (((const float*)&dn)[r] + 1e-16f);
        }
        {   // transpose hi plane: 2-way-conflict pattern (k fast, packed u64 writes)
            int k = t & 31, n4 = t >> 5;   // n4 0..31
            unsigned short r4[4];
#pragma unroll
            for (int r = 0; r < 4; ++r)
                r4[r] = (unsigned short)hbh[(n4 * 4 + r) * HS + hh * 32 + k];
            uint2 pk;
            pk.x = ((unsigned)r4[1] << 16) | r4[0];
            pk.y = ((unsigned)r4[3] << 16) | r4[2];
            *(uint2*)&hT[k * TS + n4 * 4] = pk;
        }
#pragma unroll
        for (int j = 0; j < 4; ++j) {      // Gram + P transform
            int idx = wv * 4 + j;
            int SI = idx >> 3, DJ = idx & 7;
            int ao = (SI * 16 + l15) * HS + hh * 32 + l4 * 8;
            int bo = (DJ * 16 + l15) * HS + hh * 32 + l4 * 8;
            bf16x8 ah = *(bf16x8*)&hbh[ao];
            bf16x8 al_ = *(bf16x8*)&hbl[ao];
            bf16x8 bh = *(bf16x8*)&hbh[bo];
            bf16x8 bl_ = *(bf16x8*)&hbl[bo];
            f32x4 c = {0.f, 0.f, 0.f, 0.f};
            c = __builtin_amdgcn_mfma_f32_16x16x32_bf16(ah, bh, c, 0, 0, 0);
            c = __builtin_amdgcn_mfma_f32_16x16x32_bf16(ah, bl_, c, 0, 0, 0);
            c = __builtin_amdgcn_mfma_f32_16x16x32_bf16(al_, bh, c, 0, 0, 0);
            int src0 = SI * 16 + l4 * 4;
            int dst  = DJ * 16 + l15;
            float4 al4 = *(float4*)&ALs[hh][src0];
            float ar = ARs[hh][dst];
            unsigned mw = (mask[dst][src0 >> 5] >> (src0 & 31)) & 0xFu;
            float cnt4[4] = {1.f, 1.f, 1.f, 1.f};
            {
                int s0 = dupst[dst], s1 = dupst[dst + 1];
                for (int e = s0; e < s1; ++e) {
                    int ent = dupent[e];
                    unsigned es = (unsigned)(ent >> 8) - (unsigned)src0;
                    if (es < 4u) cnt4[es] = (float)(ent & 255);
                }
            }
            unsigned short ph[4], pl[4];
#pragma unroll
            for (int r = 0; r < 4; ++r) {
                float sig = __builtin_amdgcn_rcpf(1.f + __expf(-c[r]));
                float a2 = (((const float*)&al4)[r] + ar) * sig;
                a2 = a2 >= 0.f ? a2 : 0.2f * a2;
                float pv = ((mw >> r) & 1u) ? cnt4[r] * __expf(a2) : 0.f;
                ph[r] = f2bf(pv);
                pl[r] = f2bf(pv - bf2f(ph[r]));
            }
            uint2 pk, ql;
            pk.x = ((unsigned)ph[1] << 16) | ph[0];
            pk.y = ((unsigned)ph[3] << 16) | ph[2];
            ql.x = ((unsigned)pl[1] << 16) | pl[0];
            ql.y = ((unsigned)pl[3] << 16) | pl[2];
            *(uint2*)&Pmh[dst * PS + src0] = pk;
            *(uint2*)&Pml[dst * PS + src0] = ql;
        }
        __syncthreads();                   // P + hT ready
        if (t < 128) {                     // den row-sums (2 waves) || PV (all)
            float s = 0.f;
            for (int kb = 0; kb < 16; ++kb) {
                bf16x8 p = *(bf16x8*)&Pmh[t * PS + kb * 8];
                bf16x8 q = *(bf16x8*)&Pml[t * PS + kb * 8];
#pragma unroll
                for (int e2 = 0; e2 < 8; ++e2)
                    s += bf2f((unsigned short)p[e2]) + bf2f((unsigned short)q[e2]);
            }
            den[t] = s;
        }
        num = (f32x4){0.f, 0.f, 0.f, 0.f};
#pragma unroll
        for (int kb = 0; kb < 4; ++kb) {
            int aoff = (DI * 16 + l15) * PS + kb * 32 + l4 * 8;
            bf16x8 ah = *(bf16x8*)&Pmh[aoff];
            bf16x8 al_ = *(bf16x8*)&Pml[aoff];
            bf16x8 b = *(bf16x8*)&hT[(CJ * 16 + l15) * TS + kb * 32 + l4 * 8];
            num = __builtin_amdgcn_mfma_f32_16x16x32_bf16(ah, b, num, 0, 0, 0);
            num = __builtin_amdgcn_mfma_f32_16x16x32_bf16(al_, b, num, 0, 0, 0);
        }
    }
    __syncthreads();                       // last den ready; Pm reads done
    {
        float4 dn = *(float4*)&den[DI * 16 + l4 * 4];
#pragma unroll
        for (int r = 0; r < 4; ++r)
            ((float*)&accf)[r] += ((float*)&num)[r] / (((const float*)&dn)[r] + 1e-16f);
    }

    // ---- epilogue: head mean + bias -> yout -> y + BN partials ----
    float* yout = (float*)Pm2;             // [124][33]
    {
        int c = CJ * 16 + l15;
#pragma unroll
        for (int r = 0; r < 4; ++r) {
            int n = DI * 16 + l4 * 4 + r;
            if (n < NODES) yout[n * 33 + c] = 0.25f * ((float*)&accf)[r] + bias_s[c];
        }
    }
    __syncthreads();
    if (t < 256) {
        int c = t & 31, r0 = t >> 5;       // 8 row-groups
        float s = 0.f, q = 0.f;
        for (int n = r0; n < NODES; n += 8) {
            float v = yout[n * 33 + c];
            y[(size_t)(base + n) * CC + c] = v;
            s += v; q += v * v;
        }
        bsum[r0][c] = s; bsq[r0][c] = q;
    }
    __syncthreads();
    if (t < CC) {
        float S = 0.f, Q = 0.f;
#pragma unroll
        for (int w = 0; w < 8; ++w) { S += bsum[w][t]; Q += bsq[w][t]; }
        atomicAdd(&bnacc[t], S);
        atomicAdd(&bnacc[CC + t], Q);
    }
}

// BN + relu -> xout; per-graph mean/max pool -> feat[., 124 + l*64 ...]
__global__ void bn_relu_pool(const float* __restrict__ y, const float* __restrict__ acc,
                             const float* __restrict__ gamma, const float* __restrict__ beta,
                             float* __restrict__ xout, float* __restrict__ feat, int l) {
    int g = blockIdx.x;
    int t = threadIdx.x;          // 128
    int c = t & 31, r0 = t >> 5;
    float mu = acc[c] * (1.f / NN);
    float var = acc[32 + c] * (1.f / NN) - mu * mu;
    float sc = rsqrtf(var + 1e-5f) * gamma[c];
    float bt = beta[c];
    float s = 0.f, mx = -INFINITY;
    for (int r = r0; r < NODES; r += 4) {
        int i = (g * NODES + r) * CC + c;
        float v = (y[i] - mu) * sc + bt;
        v = fmaxf(v, 0.f);
        xout[i] = v;
        s += v; mx = fmaxf(mx, v);
    }
    __shared__ float ls[128], lm[128];
    ls[t] = s; lm[t] = mx;
    __syncthreads();
    if (t < 32) {
        float S = ls[t] + ls[32 + t] + ls[64 + t] + ls[96 + t];
        float M = fmaxf(fmaxf(lm[t], lm[32 + t]), fmaxf(lm[64 + t], lm[96 + t]));
        float* fp = feat + g * FEAT_DIM + NODES + l * 64;
        fp[t] = S * (1.f / NODES);
        fp[32 + t] = M;
    }
}

// ---------------- classifier head ----------------
#define L1_GPB 4
#define L1_KS 16
#define L1_KCH 248   // NC / L1_KS = 2 chunks of 124
// grid = (NB/L1_GPB)*L1_KS = 1024 blocks, 128 threads
__global__ void lin1_part(const float* __restrict__ X, const float* __restrict__ W,
                          float* __restrict__ part) {
    int ks = blockIdx.x & (L1_KS - 1);
    int gb = (blockIdx.x >> 4) * L1_GPB;
    int t = threadIdx.x;
    int kbeg = ks * L1_KCH;
    __shared__ float xs[L1_GPB][124];
    float acc[L1_GPB] = {0.f, 0.f, 0.f, 0.f};
    for (int k0 = kbeg; k0 < kbeg + L1_KCH; k0 += 124) {
        __syncthreads();
        if (t < 124) {
#pragma unroll
            for (int rr = 0; rr < L1_GPB; ++rr) xs[rr][t] = X[(gb + rr) * NC + k0 + t];
        }
        __syncthreads();
        if (t < 124) {
#pragma unroll 4
            for (int kk = 0; kk < 124; ++kk) {
                float w = W[(k0 + kk) * 124 + t];
#pragma unroll
                for (int rr = 0; rr < L1_GPB; ++rr) acc[rr] += xs[rr][kk] * w;
            }
        }
    }
    if (t < 124)
#pragma unroll
        for (int rr = 0; rr < L1_GPB; ++rr)
            part[(ks * NB + gb + rr) * 124 + t] = acc[rr];
}

__global__ void lin1_reduce(const float* __restrict__ part, const float* __restrict__ b,
                            float* __restrict__ out1) {
    int i = blockIdx.x * blockDim.x + threadIdx.x;
    if (i >= NB * 124) return;
    int j = i % 124;
    float s = b[j];
#pragma unroll
    for (int ks = 0; ks < L1_KS; ++ks) s += part[ks * NB * 124 + i];
    out1[i] = s;
}

// 512 threads: (c = t&127, seg = t>>7 over 4 row-chunks of 64)
__global__ void bn1_relu(const float* __restrict__ out1, const float* __restrict__ gamma,
                         const float* __restrict__ beta, float* __restrict__ feat) {
    __shared__ float ps[4][124], pq[4][124], smu[124], ssc[124], sbt[124];
    int t = threadIdx.x;
    int c = t & 127, seg = t >> 7;
    float s = 0.f, q = 0.f;
    if (c < 124) {
        for (int b = seg * 64; b < seg * 64 + 64; ++b) {
            float v = out1[b * 124 + c]; s += v; q += v * v;
        }
        ps[seg][c] = s; pq[seg][c] = q;
    }
    __syncthreads();
    if (t < 124) {
        float S = ps[0][t] + ps[1][t] + ps[2][t] + ps[3][t];
        float Q = pq[0][t] + pq[1][t] + pq[2][t] + pq[3][t];
        float mu = S * (1.f / NB);
        float var = Q * (1.f / NB) - mu * mu;
        smu[t] = mu; ssc[t] = rsqrtf(var + 1e-5f) * gamma[t]; sbt[t] = beta[t];
    }
    __syncthreads();
    if (c < 124) {
        for (int b = seg * 64; b < seg * 64 + 64; ++b) {
            float v = (out1[b * 124 + c] - smu[c]) * ssc[c] + sbt[c];
            feat[b * FEAT_DIM + c] = fmaxf(v, 0.f);
        }
    }
}

// one block per graph: 320 threads = 40 outputs x 8 K-segments
__global__ void lin2_k(const float* __restrict__ feat, const float* __restrict__ W,
                       const float* __restrict__ b, float* __restrict__ out) {
    __shared__ float psum[8][40];
    int g = blockIdx.x;
    int t = threadIdx.x;
    int j = t % 40, u = t / 40;   // u 0..7
    if (u < 8) {
        int k0 = u * 40, k1 = (u == 7) ? FEAT_DIM : k0 + 40;   // last seg: 36 extra
        float s = 0.f;
        for (int k = k0; k < k1; ++k) s += feat[g * FEAT_DIM + k] * W[k * NCLS + j];
        psum[u][j] = s;
    }
    __syncthreads();
    if (t < NCLS) {
        float s = b[t];
#pragma unroll
        for (int u2 = 0; u2 < 8; ++u2) s += psum[u2][t];
        out[g * NCLS + t] = s;
    }
}

extern "C" void kernel_launch(void* const* d_in, const int* in_sizes, int n_in,
                              void* d_out, int out_size, void* d_ws, size_t ws_size,
                              hipStream_t stream) {
    const float* x      = (const float*)d_in[0];
    const int*   ei     = (const int*)d_in[1];
    const float* conv_W = (const float*)d_in[3];
    const float* att_l  = (const float*)d_in[4];
    const float* att_r  = (const float*)d_in[5];
    const float* conv_b = (const float*)d_in[6];
    const float* bn_g   = (const float*)d_in[7];
    const float* bn_b   = (const float*)d_in[8];
    const float* lin1_W = (const float*)d_in[9];
    const float* lin1_b = (const float*)d_in[10];
    const float* bn1_g  = (const float*)d_in[11];
    const float* bn1_b  = (const float*)d_in[12];
    const float* lin2_W = (const float*)d_in[13];
    const float* lin2_b = (const float*)d_in[14];

    float* ws = (float*)d_ws;
    float* y     = ws;                         // NN*32
    float* xbuf  = y + (size_t)NN * CC;        // NN*32
    float* bnacc = xbuf + (size_t)NN * CC;     // 64
    float* feat  = bnacc + 64;                 // NB*316
    float* out1  = feat + NB * FEAT_DIM;       // NB*124
    float* part  = out1 + NB * 124;            // 16*NB*124
    unsigned* gmask = (unsigned*)(part + L1_KS * NB * 124);   // NN*4
    int* gdst  = (int*)(gmask + (size_t)NN * 4);              // NB*132
    int* gdent = gdst + NB * 132;                             // NB*EXCAP

    mask_build<<<NB, 256, 0, stream>>>(ei, gmask, gdst, gdent);

    const float* xin = x;
    for (int l = 0; l < 3; ++l) {
        hipMemsetAsync(bnacc, 0, 64 * sizeof(float), stream);
        conv_graph<<<NB, 1024, 0, stream>>>(xin, conv_W + l * CC * HC,
                                            att_l + l * HC, att_r + l * HC,
                                            conv_b + l * CC, gmask, gdst, gdent,
                                            y, bnacc);
        bn_relu_pool<<<NB, 128, 0, stream>>>(y, bnacc, bn_g + l * CC, bn_b + l * CC,
                                             xbuf, feat, l);
        xin = xbuf;
    }

    lin1_part<<<(NB / L1_GPB) * L1_KS, 128, 0, stream>>>(xbuf, lin1_W, part);
    lin1_reduce<<<(NB * 124 + 255) / 256, 256, 0, stream>>>(part, lin1_b, out1);
    bn1_relu<<<1, 512, 0, stream>>>(out1, bn1_g, bn1_b, feat);
    lin2_k<<<NB, 320, 0, stream>>>(feat, lin2_W, lin2_b, (float*)d_out);
}